// Round 1
// baseline (6975.693 us; speedup 1.0000x reference)
//
#include <hip/hip_runtime.h>
#include <hip/hip_bf16.h>
#include <stdint.h>

#define FD 128
#define NNODES 50000
#define NEDGES 800000

typedef __attribute__((ext_vector_type(8))) short v8s;
typedef __attribute__((ext_vector_type(4))) float v4f;

__device__ __forceinline__ unsigned short f2bf(float f) {
  union { float f; unsigned int u; } v; v.f = f;
  unsigned int r = v.u + 0x7fffu + ((v.u >> 16) & 1u);
  return (unsigned short)(r >> 16);
}
__device__ __forceinline__ float bf2f(unsigned short b) {
  union { unsigned int u; float f; } v; v.u = ((unsigned int)b) << 16;
  return v.f;
}
// shifted softplus: log(1+e^x) - log(2), numerically stable
__device__ __forceinline__ float sspf(float x) {
  float e = __expf(-fabsf(x));
  return fmaxf(x, 0.0f) + __logf(1.0f + e) - 0.6931471805599453f;
}
// swizzled element offset within a [128][128] bf16 LDS tile (bank-conflict fix)
__device__ __forceinline__ int swz(int row, int colel) {
  return row * FD + (colel ^ ((row & 7) << 3));
}

// One 128x128x128 bf16 GEMM tile: ACT[row][k] x WBUF[n][k]^T added into acc.
// Wave wv owns cols [wv*32, wv*32+32), all 128 rows.
__device__ __forceinline__ void do_mfma(const unsigned short* ACT,
                                        const unsigned short* WBUF,
                                        int wv, int lc, int lg,
                                        v4f (&acc)[8][2]) {
  v8s Bf[2][4];
#pragma unroll
  for (int ni = 0; ni < 2; ni++) {
    int n = wv * 32 + ni * 16 + lc;
#pragma unroll
    for (int kk = 0; kk < 4; kk++) {
      int kel = kk * 32 + lg * 8;
      Bf[ni][kk] = *(const v8s*)&WBUF[swz(n, kel)];
    }
  }
#pragma unroll
  for (int mi = 0; mi < 8; mi++) {
    v8s Af[4];
    int arow = mi * 16 + lc;
#pragma unroll
    for (int kk = 0; kk < 4; kk++) {
      int kel = kk * 32 + lg * 8;
      Af[kk] = *(const v8s*)&ACT[swz(arow, kel)];
    }
#pragma unroll
    for (int ni = 0; ni < 2; ni++)
#pragma unroll
      for (int kk = 0; kk < 4; kk++)
        acc[mi][ni] = __builtin_amdgcn_mfma_f32_16x16x32_bf16(
            Af[kk], Bf[ni][kk], acc[mi][ni], 0, 0, 0);
  }
}

// ---------- prep kernels ----------

__global__ void rbf_kernel(const int* __restrict__ es, const int* __restrict__ ed,
                           const float* __restrict__ pos, float* __restrict__ rbf) {
  int e = blockIdx.x * 256 + threadIdx.x;
  if (e >= NEDGES) return;
  int s = es[e], d = ed[e];
  float dx = pos[s * 3 + 0] - pos[d * 3 + 0];
  float dy = pos[s * 3 + 1] - pos[d * 3 + 1];
  float dz = pos[s * 3 + 2] - pos[d * 3 + 2];
  float D = sqrtf(dx * dx + dy * dy + dz * dz);
  float x = D * 0.1f;
  float cut = 0.0f;
  if (x < 1.0f) {
    float x3 = x * x * x, x4 = x3 * x, x5 = x4 * x;
    cut = 1.0f - 6.0f * x5 + 15.0f * x4 - 10.0f * x3;
  }
  float eD = __expf(-D);
  float em10 = __expf(-10.0f);
  float wdt = 2.5f / (1.0f - em10);
  wdt = wdt * wdt;
#pragma unroll
  for (int k = 0; k < 5; k++) {
    float ck = 1.0f + (float)k * 0.25f * (em10 - 1.0f);
    float t = eD - ck;
    rbf[e * 5 + k] = cut * __expf(-wdt * t * t);
  }
}

// convert all weights to bf16, stored pre-swizzled so linear LDS copy + swizzled
// ds_read_b128 works. Per block b, 7 matrices: wi,wj,wd,w1_0,w2_0,w1_1,w2_1
__global__ void wconv_kernel(const float* __restrict__ wi, const float* __restrict__ wj,
                             const float* __restrict__ wd, const float* __restrict__ w1,
                             const float* __restrict__ w2, unsigned short* __restrict__ wimg) {
  int i = blockIdx.x * 256 + threadIdx.x;
  if (i >= 5 * 7 * 16384) return;
  int b = i / (7 * 16384);
  int r = i - b * 7 * 16384;
  int mtx = r >> 14;
  int idx = r & 16383;
  int n = idx >> 7, k = idx & 127;
  const float* src;
  switch (mtx) {
    case 0: src = wi + (size_t)b * 16384; break;
    case 1: src = wj + (size_t)b * 16384; break;
    case 2: src = wd + (size_t)b * 16384; break;
    case 3: src = w1 + (size_t)(b * 2 + 0) * 16384; break;
    case 4: src = w2 + (size_t)(b * 2 + 0) * 16384; break;
    case 5: src = w1 + (size_t)(b * 2 + 1) * 16384; break;
    default: src = w2 + (size_t)(b * 2 + 1) * 16384; break;
  }
  wimg[(size_t)(b * 7 + mtx) * 16384 + swz(n, k)] = f2bf(src[idx]);
}

__global__ void h0_kernel(const int* __restrict__ at, const float* __restrict__ emb,
                          float* __restrict__ h) {
  int i = blockIdx.x * 256 + threadIdx.x;
  int n = i >> 7, c = i & 127;
  h[i] = emb[at[n] * FD + c];
}

// ---------- per-block node kernel: x=ssp(h); hi=x@wi^T+bi (fp32); hj=x@wj^T+bj (bf16) ----------

__global__ __launch_bounds__(256, 2) void node_kernel(
    const float* __restrict__ h, const unsigned short* __restrict__ wi_img,
    const unsigned short* __restrict__ wj_img, const float* __restrict__ bi,
    const float* __restrict__ bj, float* __restrict__ hi_f,
    unsigned short* __restrict__ hj_bf)
{
  __shared__ unsigned short ACT[FD * FD];
  __shared__ unsigned short WBUF[FD * FD];
  const int tid = threadIdx.x;
  const int wv = tid >> 6;
  const int l = tid & 63;
  const int lc = l & 15;
  const int lg = l >> 4;
  const int col0 = wv * 32 + lc;
  const int rbase = lg * 4;
  const int n0 = blockIdx.x * 128;

  float bvi[2], bvj[2];
#pragma unroll
  for (int ni = 0; ni < 2; ni++) {
    bvi[ni] = bi[col0 + ni * 16];
    bvj[ni] = bj[col0 + ni * 16];
  }

#pragma unroll
  for (int mi = 0; mi < 8; mi++) {
#pragma unroll
    for (int j = 0; j < 4; j++) {
      int row = mi * 16 + rbase + j;
      int n = n0 + row;
#pragma unroll
      for (int ni = 0; ni < 2; ni++) {
        int c = col0 + ni * 16;
        float x = 0.0f;
        if (n < NNODES) x = sspf(h[n * FD + c]);
        ACT[swz(row, c)] = f2bf(x);
      }
    }
  }
  {
    const uint4* src = (const uint4*)wi_img;
    uint4* dst = (uint4*)WBUF;
#pragma unroll
    for (int i = 0; i < 8; i++) dst[tid + i * 256] = src[tid + i * 256];
  }
  __syncthreads();

  v4f acc[8][2];
#pragma unroll
  for (int mi = 0; mi < 8; mi++)
#pragma unroll
    for (int ni = 0; ni < 2; ni++)
      acc[mi][ni] = (v4f){bvi[ni], bvi[ni], bvi[ni], bvi[ni]};
  do_mfma(ACT, WBUF, wv, lc, lg, acc);
#pragma unroll
  for (int mi = 0; mi < 8; mi++) {
#pragma unroll
    for (int j = 0; j < 4; j++) {
      int row = mi * 16 + rbase + j;
      int n = n0 + row;
      if (n < NNODES) {
#pragma unroll
        for (int ni = 0; ni < 2; ni++)
          hi_f[n * FD + col0 + ni * 16] = acc[mi][ni][j];
      }
    }
  }
  __syncthreads();
  {
    const uint4* src = (const uint4*)wj_img;
    uint4* dst = (uint4*)WBUF;
#pragma unroll
    for (int i = 0; i < 8; i++) dst[tid + i * 256] = src[tid + i * 256];
  }
  __syncthreads();
#pragma unroll
  for (int mi = 0; mi < 8; mi++)
#pragma unroll
    for (int ni = 0; ni < 2; ni++)
      acc[mi][ni] = (v4f){bvj[ni], bvj[ni], bvj[ni], bvj[ni]};
  do_mfma(ACT, WBUF, wv, lc, lg, acc);
#pragma unroll
  for (int mi = 0; mi < 8; mi++) {
#pragma unroll
    for (int j = 0; j < 4; j++) {
      int row = mi * 16 + rbase + j;
      int n = n0 + row;
      if (n < NNODES) {
#pragma unroll
        for (int ni = 0; ni < 2; ni++)
          hj_bf[n * FD + col0 + ni * 16] = f2bf(acc[mi][ni][j]);
      }
    }
  }
}

// ---------- per-block fused edge kernel: 9 chained GEMVs + atomic segment-sum ----------
// Layers: 0:W1_0 1:W2_0 2:W1_1 3:W2_1 4:Wd 5:W1_0 6:W2_0 7:W1_1 8:W2_1
// mat idx in wimg block: wd=2, w1_0=3, w2_0=4, w1_1=5, w2_1=6

__global__ __launch_bounds__(256, 2) void edge_kernel(
    const float* __restrict__ hi_f, const unsigned short* __restrict__ hj_bf,
    const float* __restrict__ rbf, const int* __restrict__ esrc,
    const int* __restrict__ edst, const unsigned short* __restrict__ wimg,
    const float* __restrict__ rb1, const float* __restrict__ rb2,
    const float* __restrict__ bd, const float* __restrict__ uvec,
    const float* __restrict__ k2f, float* __restrict__ outp)
{
  __shared__ unsigned short ACT[FD * FD];
  __shared__ unsigned short WBUF[FD * FD];
  __shared__ float RBF5[128 * 5];
  __shared__ int EDG[256];

  const int tid = threadIdx.x;
  const int wv = tid >> 6;
  const int l = tid & 63;
  const int lc = l & 15;
  const int lg = l >> 4;
  const int col0 = wv * 32 + lc;
  const int rbase = lg * 4;
  const int e0 = blockIdx.x * 128;

  for (int i = tid; i < 128; i += 256) {
    EDG[i] = esrc[e0 + i];
    EDG[128 + i] = edst[e0 + i];
  }
  for (int i = tid; i < 640; i += 256) RBF5[i] = rbf[e0 * 5 + i];

  float bt0[2], bt1[2], bt2[2], bt3[2], bt4[2], uu[2], kc[2][5];
#pragma unroll
  for (int ni = 0; ni < 2; ni++) {
    int c = col0 + ni * 16;
    bt0[ni] = rb1[c];
    bt1[ni] = rb2[c];
    bt2[ni] = rb1[FD + c];
    bt3[ni] = rb2[FD + c];
    bt4[ni] = bd[c];
    uu[ni] = uvec[c];
#pragma unroll
    for (int k = 0; k < 5; k++) kc[ni][k] = k2f[c * 5 + k];
  }
  __syncthreads();

  // initial gather: m = ai + g*hj[src];  ACT = bf16(ssp(m))  (skip path m stays fp32)
  float m[8][2][4];
#pragma unroll
  for (int mi = 0; mi < 8; mi++) {
#pragma unroll
    for (int j = 0; j < 4; j++) {
      int row = mi * 16 + rbase + j;
      int s = EDG[row];
      int d = EDG[128 + row];
      float r5[5];
#pragma unroll
      for (int k = 0; k < 5; k++) r5[k] = RBF5[row * 5 + k];
#pragma unroll
      for (int ni = 0; ni < 2; ni++) {
        int c = col0 + ni * 16;
        float ai = hi_f[d * FD + c];
        float hjv = bf2f(hj_bf[s * FD + c]);
        float g = r5[0] * kc[ni][0] + r5[1] * kc[ni][1] + r5[2] * kc[ni][2]
                + r5[3] * kc[ni][3] + r5[4] * kc[ni][4];
        float m0 = ai + g * hjv;
        m[mi][ni][j] = m0;
        ACT[swz(row, c)] = f2bf(sspf(m0));
      }
    }
  }
  {
    const uint4* src = (const uint4*)(wimg + 3 * 16384);  // w1_0
    uint4* dst = (uint4*)WBUF;
#pragma unroll
    for (int i = 0; i < 8; i++) dst[tid + i * 256] = src[tid + i * 256];
  }
  __syncthreads();

#pragma unroll 1
  for (int L = 0; L < 9; L++) {
    v4f acc[8][2];
    if (L == 4) {
      // acc = u*ai + bd  (trunk term in fp32, never quantized)
#pragma unroll
      for (int mi = 0; mi < 8; mi++) {
#pragma unroll
        for (int j = 0; j < 4; j++) {
          int row = mi * 16 + rbase + j;
          int d = EDG[128 + row];
#pragma unroll
          for (int ni = 0; ni < 2; ni++)
            acc[mi][ni][j] = uu[ni] * hi_f[d * FD + col0 + ni * 16] + bt4[ni];
        }
      }
    } else {
      int Lr = (L < 4) ? L : L - 5;
      float bv[2];
#pragma unroll
      for (int ni = 0; ni < 2; ni++)
        bv[ni] = (Lr == 0) ? bt0[ni] : (Lr == 1) ? bt1[ni] : (Lr == 2) ? bt2[ni] : bt3[ni];
#pragma unroll
      for (int mi = 0; mi < 8; mi++)
#pragma unroll
        for (int ni = 0; ni < 2; ni++)
          acc[mi][ni] = (v4f){bv[ni], bv[ni], bv[ni], bv[ni]};
    }

    do_mfma(ACT, WBUF, wv, lc, lg, acc);
    __syncthreads();  // all ACT/WBUF reads done

    const bool isAcc = (L == 1) || (L == 3) || (L == 6) || (L == 8);
    if (L == 4) {
#pragma unroll
      for (int mi = 0; mi < 8; mi++)
#pragma unroll
        for (int ni = 0; ni < 2; ni++)
#pragma unroll
          for (int j = 0; j < 4; j++) m[mi][ni][j] = acc[mi][ni][j];
    } else if (isAcc) {
#pragma unroll
      for (int mi = 0; mi < 8; mi++)
#pragma unroll
        for (int ni = 0; ni < 2; ni++)
#pragma unroll
          for (int j = 0; j < 4; j++) m[mi][ni][j] += acc[mi][ni][j];
    }

    if (L < 8) {
      const bool wssp = isAcc || (L == 4);
#pragma unroll
      for (int mi = 0; mi < 8; mi++) {
#pragma unroll
        for (int j = 0; j < 4; j++) {
          int row = mi * 16 + rbase + j;
#pragma unroll
          for (int ni = 0; ni < 2; ni++) {
            int c = col0 + ni * 16;
            float v = wssp ? sspf(m[mi][ni][j]) : acc[mi][ni][j];
            ACT[swz(row, c)] = f2bf(v);
          }
        }
      }
      int Ln = L + 1;
      int mat = (Ln == 4) ? 2 : ((Ln < 4) ? 3 + Ln : Ln - 2);
      const uint4* src = (const uint4*)(wimg + (size_t)mat * 16384);
      uint4* dst = (uint4*)WBUF;
#pragma unroll
      for (int i = 0; i < 8; i++) dst[tid + i * 256] = src[tid + i * 256];
      __syncthreads();
    }
  }

  // segment-sum scatter (fp32 atomics, device scope)
#pragma unroll
  for (int mi = 0; mi < 8; mi++) {
#pragma unroll
    for (int j = 0; j < 4; j++) {
      int row = mi * 16 + rbase + j;
      int d = EDG[128 + row];
#pragma unroll
      for (int ni = 0; ni < 2; ni++)
        atomicAdd(&outp[d * FD + col0 + ni * 16], m[mi][ni][j]);
    }
  }
}

extern "C" void kernel_launch(void* const* d_in, const int* in_sizes, int n_in,
                              void* d_out, int out_size, void* d_ws, size_t ws_size,
                              hipStream_t stream) {
  (void)in_sizes; (void)n_in; (void)out_size; (void)ws_size;
  const int* at = (const int*)d_in[0];
  const int* es = (const int*)d_in[1];
  const int* ed = (const int*)d_in[2];
  const float* pos = (const float*)d_in[3];
  const float* emb = (const float*)d_in[4];
  const float* k2f = (const float*)d_in[5];
  const float* wi = (const float*)d_in[6];
  const float* bi = (const float*)d_in[7];
  const float* wj = (const float*)d_in[8];
  const float* bj = (const float*)d_in[9];
  const float* wd = (const float*)d_in[10];
  const float* bd = (const float*)d_in[11];
  const float* u = (const float*)d_in[12];
  const float* rw1 = (const float*)d_in[13];
  const float* rb1 = (const float*)d_in[14];
  const float* rw2 = (const float*)d_in[15];
  const float* rb2 = (const float*)d_in[16];

  char* w = (char*)d_ws;
  float* rbf = (float*)w;                     w += (size_t)NEDGES * 5 * 4;
  float* hi_f = (float*)w;                    w += (size_t)NNODES * FD * 4;
  unsigned short* hj_bf = (unsigned short*)w; w += (size_t)NNODES * FD * 2;
  float* hA = (float*)w;                      w += (size_t)NNODES * FD * 4;
  unsigned short* wimg = (unsigned short*)w;  w += (size_t)5 * 7 * 16384 * 2;

  rbf_kernel<<<(NEDGES + 255) / 256, 256, 0, stream>>>(es, ed, pos, rbf);
  wconv_kernel<<<(5 * 7 * 16384 + 255) / 256, 256, 0, stream>>>(wi, wj, wd, rw1, rw2, wimg);
  h0_kernel<<<(NNODES * FD) / 256, 256, 0, stream>>>(at, emb, hA);

  // h ping-pongs between hA and d_out; final block lands in d_out.
  float* hcur = hA;
  for (int b = 0; b < 5; b++) {
    node_kernel<<<(NNODES + 127) / 128, 256, 0, stream>>>(
        hcur, wimg + (size_t)(b * 7 + 0) * 16384, wimg + (size_t)(b * 7 + 1) * 16384,
        bi + b * FD, bj + b * FD, hi_f, hj_bf);
    float* tgt = (b & 1) ? hA : (float*)d_out;
    hipMemsetAsync(tgt, 0, (size_t)NNODES * FD * 4, stream);
    edge_kernel<<<NEDGES / 128, 256, 0, stream>>>(
        hi_f, hj_bf, rbf, es, ed, wimg + (size_t)b * 7 * 16384,
        rb1 + (size_t)b * 2 * FD, rb2 + (size_t)b * 2 * FD, bd + b * FD,
        u + b * FD, k2f + (size_t)b * FD * 5, tgt);
    hcur = tgt;
  }
}

// Round 2
// 5512.445 us; speedup vs baseline: 1.2654x; 1.2654x over previous
//
#include <hip/hip_runtime.h>
#include <stdint.h>

#define FD 128
#define NNODES 50000
#define NEDGES 800000
#define EB 64  // edges per block

typedef __attribute__((ext_vector_type(8))) short v8s;
typedef __attribute__((ext_vector_type(4))) float v4f;

__device__ __forceinline__ unsigned short f2bf(float f) {
  union { float f; unsigned int u; } v; v.f = f;
  unsigned int r = v.u + 0x7fffu + ((v.u >> 16) & 1u);
  return (unsigned short)(r >> 16);
}
__device__ __forceinline__ float bf2f(unsigned short b) {
  union { unsigned int u; float f; } v; v.u = ((unsigned int)b) << 16;
  return v.f;
}
// shifted softplus: log(1+e^x) - log(2), numerically stable
__device__ __forceinline__ float sspf(float x) {
  float e = __expf(-fabsf(x));
  return fmaxf(x, 0.0f) + __logf(1.0f + e) - 0.6931471805599453f;
}
// swizzled element offset within a [rows][128] bf16 LDS tile (bank-conflict fix)
__device__ __forceinline__ int swz(int row, int colel) {
  return row * FD + (colel ^ ((row & 7) << 3));
}

// Load this wave's B-fragments (8 x 16B, coalesced) from fragment-packed weights.
// wfrag already offset to this wave's 8KB region.
__device__ __forceinline__ void load_bfrag(const unsigned short* __restrict__ wfrag,
                                           int l, v8s (&Bf)[2][4]) {
#pragma unroll
  for (int ni = 0; ni < 2; ni++)
#pragma unroll
    for (int kk = 0; kk < 4; kk++)
      Bf[ni][kk] = *(const v8s*)(wfrag + (((ni << 2) + kk) << 9) + (l << 3));
}

// MI*16 rows x 32 cols output tile: ACT[row][k] (swizzled LDS) x Bf^T into acc.
template <int MI>
__device__ __forceinline__ void mfma_frag(const unsigned short* ACT, const v8s (&Bf)[2][4],
                                          int lc, int lg, v4f (&acc)[MI][2]) {
#pragma unroll
  for (int mi = 0; mi < MI; mi++) {
    v8s Af[4];
    int arow = mi * 16 + lc;
#pragma unroll
    for (int kk = 0; kk < 4; kk++)
      Af[kk] = *(const v8s*)&ACT[swz(arow, kk * 32 + lg * 8)];
#pragma unroll
    for (int ni = 0; ni < 2; ni++)
#pragma unroll
      for (int kk = 0; kk < 4; kk++)
        acc[mi][ni] = __builtin_amdgcn_mfma_f32_16x16x32_bf16(
            Af[kk], Bf[ni][kk], acc[mi][ni], 0, 0, 0);
  }
}

// ---------- prep kernels ----------

__global__ void rbf_kernel(const int* __restrict__ es, const int* __restrict__ ed,
                           const float* __restrict__ pos, float* __restrict__ rbf) {
  int e = blockIdx.x * 256 + threadIdx.x;
  if (e >= NEDGES) return;
  int s = es[e], d = ed[e];
  float dx = pos[s * 3 + 0] - pos[d * 3 + 0];
  float dy = pos[s * 3 + 1] - pos[d * 3 + 1];
  float dz = pos[s * 3 + 2] - pos[d * 3 + 2];
  float D = sqrtf(dx * dx + dy * dy + dz * dz);
  float x = D * 0.1f;
  float cut = 0.0f;
  if (x < 1.0f) {
    float x3 = x * x * x, x4 = x3 * x, x5 = x4 * x;
    cut = 1.0f - 6.0f * x5 + 15.0f * x4 - 10.0f * x3;
  }
  float eD = __expf(-D);
  float em10 = __expf(-10.0f);
  float wdt = 2.5f / (1.0f - em10);
  wdt = wdt * wdt;
#pragma unroll
  for (int k = 0; k < 5; k++) {
    float ck = 1.0f + (float)k * 0.25f * (em10 - 1.0f);
    float t = eD - ck;
    rbf[e * 5 + k] = cut * __expf(-wdt * t * t);
  }
}

// Convert weights to bf16 in MFMA B-FRAGMENT order:
// within a matrix: off = ((nt*4)+kk)*512 + l*8 + j  holds W[nt*16+(l&15)][kk*32+(l>>4)*8+j]
// Per block b, 7 matrices: 0:wi 1:wj 2:wd 3:w1_0 4:w2_0 5:w1_1 6:w2_1
__global__ void wconv_kernel(const float* __restrict__ wi, const float* __restrict__ wj,
                             const float* __restrict__ wd, const float* __restrict__ w1,
                             const float* __restrict__ w2, unsigned short* __restrict__ wimg2) {
  int i = blockIdx.x * 256 + threadIdx.x;
  if (i >= 5 * 7 * 16384) return;
  int b = i / (7 * 16384);
  int r = i - b * 7 * 16384;
  int mtx = r >> 14;
  int off = r & 16383;
  int j = off & 7;
  int l = (off >> 3) & 63;
  int kk = (off >> 9) & 3;
  int nt = off >> 11;
  int row = nt * 16 + (l & 15);
  int col = kk * 32 + (l >> 4) * 8 + j;
  const float* src;
  switch (mtx) {
    case 0: src = wi + (size_t)b * 16384; break;
    case 1: src = wj + (size_t)b * 16384; break;
    case 2: src = wd + (size_t)b * 16384; break;
    case 3: src = w1 + (size_t)(b * 2 + 0) * 16384; break;
    case 4: src = w2 + (size_t)(b * 2 + 0) * 16384; break;
    case 5: src = w1 + (size_t)(b * 2 + 1) * 16384; break;
    default: src = w2 + (size_t)(b * 2 + 1) * 16384; break;
  }
  wimg2[(size_t)(b * 7 + mtx) * 16384 + off] = f2bf(src[row * 128 + col]);
}

__global__ void h0_kernel(const int* __restrict__ at, const float* __restrict__ emb,
                          float* __restrict__ h) {
  int i = blockIdx.x * 256 + threadIdx.x;
  int n = i >> 7, c = i & 127;
  h[i] = emb[at[n] * FD + c];
}

// ---------- per-block node kernel: x=ssp(h); hi=x@wi^T+bi (fp32); hj=x@wj^T+bj (bf16) ----------

__global__ __launch_bounds__(256, 3) void node_kernel(
    const float* __restrict__ h, const unsigned short* __restrict__ wblk,
    const float* __restrict__ bi, const float* __restrict__ bj,
    float* __restrict__ hi_f, unsigned short* __restrict__ hj_bf)
{
  __shared__ unsigned short ACT[FD * FD];
  const int tid = threadIdx.x;
  const int wv = tid >> 6;
  const int l = tid & 63;
  const int lc = l & 15;
  const int lg = l >> 4;
  const int col0 = wv * 32 + lc;
  const int rbase = lg * 4;
  const int n0 = blockIdx.x * 128;

  v8s Bfi[2][4], Bfj[2][4];
  load_bfrag(wblk + 0 * 16384 + wv * 4096, l, Bfi);
  load_bfrag(wblk + 1 * 16384 + wv * 4096, l, Bfj);

  float bvi[2], bvj[2];
#pragma unroll
  for (int ni = 0; ni < 2; ni++) {
    bvi[ni] = bi[col0 + ni * 16];
    bvj[ni] = bj[col0 + ni * 16];
  }

#pragma unroll
  for (int mi = 0; mi < 8; mi++) {
#pragma unroll
    for (int j = 0; j < 4; j++) {
      int row = mi * 16 + rbase + j;
      int n = n0 + row;
      int xorv = (row & 7) << 3;
#pragma unroll
      for (int ni = 0; ni < 2; ni++) {
        int c = col0 + ni * 16;
        float x = 0.0f;
        if (n < NNODES) x = sspf(h[n * FD + c]);
        ACT[row * FD + (c ^ xorv)] = f2bf(x);
      }
    }
  }
  __syncthreads();

  v4f acc[8][2];
#pragma unroll
  for (int mi = 0; mi < 8; mi++)
#pragma unroll
    for (int ni = 0; ni < 2; ni++)
      acc[mi][ni] = (v4f){bvi[ni], bvi[ni], bvi[ni], bvi[ni]};
  mfma_frag<8>(ACT, Bfi, lc, lg, acc);
#pragma unroll
  for (int mi = 0; mi < 8; mi++) {
#pragma unroll
    for (int j = 0; j < 4; j++) {
      int n = n0 + mi * 16 + rbase + j;
      if (n < NNODES) {
#pragma unroll
        for (int ni = 0; ni < 2; ni++)
          hi_f[n * FD + col0 + ni * 16] = acc[mi][ni][j];
      }
    }
  }

#pragma unroll
  for (int mi = 0; mi < 8; mi++)
#pragma unroll
    for (int ni = 0; ni < 2; ni++)
      acc[mi][ni] = (v4f){bvj[ni], bvj[ni], bvj[ni], bvj[ni]};
  mfma_frag<8>(ACT, Bfj, lc, lg, acc);
#pragma unroll
  for (int mi = 0; mi < 8; mi++) {
#pragma unroll
    for (int j = 0; j < 4; j++) {
      int n = n0 + mi * 16 + rbase + j;
      if (n < NNODES) {
#pragma unroll
        for (int ni = 0; ni < 2; ni++)
          hj_bf[n * FD + col0 + ni * 16] = f2bf(acc[mi][ni][j]);
      }
    }
  }
}

// ---------- per-block fused edge kernel: 9 chained GEMVs + atomic segment-sum ----------
// Layers: 0:w1_0 1:w2_0 2:w1_1 3:w2_1 4:wd 5:w1_0 6:w2_0 7:w1_1 8:w2_1

__global__ __launch_bounds__(256, 3) void edge_kernel(
    const float* __restrict__ hi_f, const unsigned short* __restrict__ hj_bf,
    const float* __restrict__ rbf, const int* __restrict__ esrc,
    const int* __restrict__ edst, const unsigned short* __restrict__ wblk,
    const float* __restrict__ rb1, const float* __restrict__ rb2,
    const float* __restrict__ bd, const float* __restrict__ uvec,
    const float* __restrict__ k2f, float* __restrict__ outp)
{
  __shared__ unsigned short ACTb[2][EB * FD];  // double-buffered activations
  __shared__ float RBF5[EB * 5];
  __shared__ int EDG[2 * EB];

  const int tid = threadIdx.x;
  const int wv = tid >> 6;
  const int l = tid & 63;
  const int lc = l & 15;
  const int lg = l >> 4;
  const int col0 = wv * 32 + lc;
  const int rbase = lg * 4;
  const int e0 = blockIdx.x * EB;

  for (int i = tid; i < 2 * EB; i += 256) {
    EDG[i] = (i < EB) ? esrc[e0 + i] : edst[e0 + i - EB];
  }
  for (int i = tid; i < EB * 5; i += 256) RBF5[i] = rbf[e0 * 5 + i];

  float bt0[2], bt1[2], bt2[2], bt3[2], bt4[2], uu[2], kc[2][5];
#pragma unroll
  for (int ni = 0; ni < 2; ni++) {
    int c = col0 + ni * 16;
    bt0[ni] = rb1[c];
    bt1[ni] = rb2[c];
    bt2[ni] = rb1[FD + c];
    bt3[ni] = rb2[FD + c];
    bt4[ni] = bd[c];
    uu[ni] = uvec[c];
#pragma unroll
    for (int k = 0; k < 5; k++) kc[ni][k] = k2f[c * 5 + k];
  }
  __syncthreads();  // EDG/RBF5 ready

  // initial gather: m = ai + g*hj[src];  ACT[0] = bf16(ssp(m)); skip path m stays fp32
  float m[4][2][4];
#pragma unroll
  for (int mi = 0; mi < 4; mi++) {
#pragma unroll
    for (int j = 0; j < 4; j++) {
      int row = mi * 16 + rbase + j;
      int s = EDG[row];
      int d = EDG[EB + row];
      int xorv = (row & 7) << 3;
      float r5[5];
#pragma unroll
      for (int k = 0; k < 5; k++) r5[k] = RBF5[row * 5 + k];
#pragma unroll
      for (int ni = 0; ni < 2; ni++) {
        int c = col0 + ni * 16;
        float ai = hi_f[d * FD + c];
        float hjv = bf2f(hj_bf[s * FD + c]);
        float g = r5[0] * kc[ni][0] + r5[1] * kc[ni][1] + r5[2] * kc[ni][2]
                + r5[3] * kc[ni][3] + r5[4] * kc[ni][4];
        float m0 = ai + g * hjv;
        m[mi][ni][j] = m0;
        ACTb[0][row * FD + (c ^ xorv)] = f2bf(sspf(m0));
      }
    }
  }

  int buf = 0;
#pragma unroll 1
  for (int L = 0; L < 9; L++) {
    // B-fragments for this layer: direct from global (L2-resident), coalesced
    int mat = (L == 4) ? 2 : ((L < 4) ? 3 + L : L - 2);
    v8s Bf[2][4];
    load_bfrag(wblk + mat * 16384 + wv * 4096, l, Bf);

    v4f acc[4][2];
    if (L == 4) {
      // acc = u*ai + bd (trunk term fp32; loads issued pre-barrier to hide latency)
#pragma unroll
      for (int mi = 0; mi < 4; mi++) {
#pragma unroll
        for (int j = 0; j < 4; j++) {
          int d = EDG[EB + mi * 16 + rbase + j];
#pragma unroll
          for (int ni = 0; ni < 2; ni++)
            acc[mi][ni][j] = uu[ni] * hi_f[d * FD + col0 + ni * 16] + bt4[ni];
        }
      }
    } else {
      int Lr = (L < 4) ? L : L - 5;
      float bv[2];
#pragma unroll
      for (int ni = 0; ni < 2; ni++)
        bv[ni] = (Lr == 0) ? bt0[ni] : (Lr == 1) ? bt1[ni] : (Lr == 2) ? bt2[ni] : bt3[ni];
#pragma unroll
      for (int mi = 0; mi < 4; mi++)
#pragma unroll
        for (int ni = 0; ni < 2; ni++)
          acc[mi][ni] = (v4f){bv[ni], bv[ni], bv[ni], bv[ni]};
    }

    __syncthreads();  // ACT[buf] writes done; prior reads of ACT[buf^1] also done (program order)
    mfma_frag<4>(&ACTb[buf][0], Bf, lc, lg, acc);

    const bool isAcc = (L == 1) || (L == 3) || (L == 6) || (L == 8);
    if (L == 4) {
#pragma unroll
      for (int mi = 0; mi < 4; mi++)
#pragma unroll
        for (int ni = 0; ni < 2; ni++)
#pragma unroll
          for (int j = 0; j < 4; j++) m[mi][ni][j] = acc[mi][ni][j];
    } else if (isAcc) {
#pragma unroll
      for (int mi = 0; mi < 4; mi++)
#pragma unroll
        for (int ni = 0; ni < 2; ni++)
#pragma unroll
          for (int j = 0; j < 4; j++) m[mi][ni][j] += acc[mi][ni][j];
    }

    if (L < 8) {
      const bool wssp = isAcc || (L == 4);
      unsigned short* An = &ACTb[buf ^ 1][0];
#pragma unroll
      for (int mi = 0; mi < 4; mi++) {
#pragma unroll
        for (int j = 0; j < 4; j++) {
          int row = mi * 16 + rbase + j;
          int xorv = (row & 7) << 3;
#pragma unroll
          for (int ni = 0; ni < 2; ni++) {
            int c = col0 + ni * 16;
            float v = wssp ? sspf(m[mi][ni][j]) : acc[mi][ni][j];
            An[row * FD + (c ^ xorv)] = f2bf(v);
          }
        }
      }
    }
    buf ^= 1;
  }

  // segment-sum scatter (fp32 atomics, device scope)
#pragma unroll
  for (int mi = 0; mi < 4; mi++) {
#pragma unroll
    for (int j = 0; j < 4; j++) {
      int d = EDG[EB + mi * 16 + rbase + j];
#pragma unroll
      for (int ni = 0; ni < 2; ni++)
        atomicAdd(&outp[d * FD + col0 + ni * 16], m[mi][ni][j]);
    }
  }
}

extern "C" void kernel_launch(void* const* d_in, const int* in_sizes, int n_in,
                              void* d_out, int out_size, void* d_ws, size_t ws_size,
                              hipStream_t stream) {
  (void)in_sizes; (void)n_in; (void)out_size; (void)ws_size;
  const int* at = (const int*)d_in[0];
  const int* es = (const int*)d_in[1];
  const int* ed = (const int*)d_in[2];
  const float* pos = (const float*)d_in[3];
  const float* emb = (const float*)d_in[4];
  const float* k2f = (const float*)d_in[5];
  const float* wi = (const float*)d_in[6];
  const float* bi = (const float*)d_in[7];
  const float* wj = (const float*)d_in[8];
  const float* bj = (const float*)d_in[9];
  const float* wd = (const float*)d_in[10];
  const float* bd = (const float*)d_in[11];
  const float* u = (const float*)d_in[12];
  const float* rw1 = (const float*)d_in[13];
  const float* rb1 = (const float*)d_in[14];
  const float* rw2 = (const float*)d_in[15];
  const float* rb2 = (const float*)d_in[16];

  char* w = (char*)d_ws;
  float* rbf = (float*)w;                     w += (size_t)NEDGES * 5 * 4;
  float* hi_f = (float*)w;                    w += (size_t)NNODES * FD * 4;
  unsigned short* hj_bf = (unsigned short*)w; w += (size_t)NNODES * FD * 2;
  float* hA = (float*)w;                      w += (size_t)NNODES * FD * 4;
  unsigned short* wimg2 = (unsigned short*)w; w += (size_t)5 * 7 * 16384 * 2;

  rbf_kernel<<<(NEDGES + 255) / 256, 256, 0, stream>>>(es, ed, pos, rbf);
  wconv_kernel<<<(5 * 7 * 16384 + 255) / 256, 256, 0, stream>>>(wi, wj, wd, rw1, rw2, wimg2);
  h0_kernel<<<(NNODES * FD) / 256, 256, 0, stream>>>(at, emb, hA);

  // h ping-pongs between hA and d_out; final block lands in d_out.
  float* hcur = hA;
  for (int b = 0; b < 5; b++) {
    node_kernel<<<(NNODES + 127) / 128, 256, 0, stream>>>(
        hcur, wimg2 + (size_t)b * 7 * 16384, bi + b * FD, bj + b * FD, hi_f, hj_bf);
    float* tgt = (b & 1) ? hA : (float*)d_out;
    hipMemsetAsync(tgt, 0, (size_t)NNODES * FD * 4, stream);
    edge_kernel<<<NEDGES / EB, 256, 0, stream>>>(
        hi_f, hj_bf, rbf, es, ed, wimg2 + (size_t)b * 7 * 16384,
        rb1 + (size_t)b * 2 * FD, rb2 + (size_t)b * 2 * FD, bd + b * FD,
        u + b * FD, k2f + (size_t)b * FD * 5, tgt);
    hcur = tgt;
  }
}